// Round 5
// baseline (872.570 us; speedup 1.0000x reference)
//
#include <hip/hip_runtime.h>
#include <stdint.h>
#include <math.h>

static constexpr int B_   = 4;
static constexpr int N1   = 255780;   // total anchors per image across 5 levels
static constexpr int PRE  = 6000;
static constexpr int POST = 1000;
static constexpr int MWORDS = 94;     // ceil(6000/64)
static constexpr int NCAND = 8192;    // candidate capacity per image
static constexpr float NEGF = -1000000000.0f;

__device__ __constant__ int c_OFF[6] = {0,192000,240000,252000,255000,255780};
__device__ __constant__ int c_H[5]   = {200,100,50,25,13};
__device__ __constant__ int c_W[5]   = {320,160,80,40,20};
__device__ __constant__ int c_S[5]   = {4,8,16,32,64};

struct Ptrs { const float* cls[5]; const float* bbox[5]; };

// ---------- helpers ----------
__device__ __forceinline__ unsigned forder(float f) {
  unsigned u = __float_as_uint(f);
  return (u & 0x80000000u) ? ~u : (u | 0x80000000u);
}
__device__ __forceinline__ float funorder(unsigned u) {
  u = (u & 0x80000000u) ? (u & 0x7FFFFFFFu) : ~u;
  return __uint_as_float(u);
}
__device__ __forceinline__ int bucket_of(float s) {
  int bk = (int)(s * 4096.0f);
  return max(0, min(4095, bk));
}

// base anchor (legacy +1 convention), double math == numpy float64, rint == np.round
__device__ __forceinline__ void anchor_for(int lvl, int a, float& ax1, float& ay1, float& ax2, float& ay2) {
  int st = c_S[lvl];
  double size = (double)st * (double)st;
  double c = 0.5 * (double)(st - 1);
  double r = (a == 0) ? 0.5 : (a == 1) ? 1.0 : 2.0;
  double ws = rint(sqrt(size / r));
  double hs = rint(ws * r);
  double w2 = ws * 8.0, h2 = hs * 8.0;
  ax1 = (float)(c - 0.5 * (w2 - 1.0));
  ay1 = (float)(c - 0.5 * (h2 - 1.0));
  ax2 = (float)(c + 0.5 * (w2 - 1.0));
  ay2 = (float)(c + 0.5 * (h2 - 1.0));
}

// decode one anchor exactly as the reference (per-op f32 rounding, no FMA)
__device__ __forceinline__ void decode_one(const Ptrs& P, int b, int gi, float wlim, float hlim,
                                           float& x1, float& y1, float& x2, float& y2, bool& valid) {
  int lvl = (gi >= c_OFF[4]) ? 4 : (gi >= c_OFF[3]) ? 3 : (gi >= c_OFF[2]) ? 2 : (gi >= c_OFF[1]) ? 1 : 0;
  int rem = gi - c_OFF[lvl];
  int a = rem % 3;
  int pos = rem / 3;
  int W = c_W[lvl];
  int h = pos / W, w = pos - h * W;
  size_t hw = (size_t)c_H[lvl] * W;
  const float* bb = P.bbox[lvl] + ((size_t)b * 12 + 4 * a) * hw + (size_t)h * W + w;
  float d0 = bb[0], d1 = bb[hw], d2 = bb[2 * hw], d3 = bb[3 * hw];

  float ax1, ay1, ax2, ay2;
  anchor_for(lvl, a, ax1, ay1, ax2, ay2);
  int st = c_S[lvl];
  float sx = (float)(w * st), sy = (float)(h * st);
  ax1 += sx; ax2 += sx; ay1 += sy; ay2 += sy;   // exact integers

  float aw  = __fadd_rn(__fsub_rn(ax2, ax1), 1.0f);
  float ah  = __fadd_rn(__fsub_rn(ay2, ay1), 1.0f);
  float acx = __fadd_rn(ax1, __fmul_rn(0.5f, __fsub_rn(aw, 1.0f)));
  float acy = __fadd_rn(ay1, __fmul_rn(0.5f, __fsub_rn(ah, 1.0f)));
  float ew  = (float)exp((double)d2);
  float eh  = (float)exp((double)d3);
  float pcx = __fadd_rn(__fmul_rn(d0, aw), acx);
  float pcy = __fadd_rn(__fmul_rn(d1, ah), acy);
  float pw  = __fmul_rn(ew, aw);
  float ph  = __fmul_rn(eh, ah);
  float hwf = __fmul_rn(0.5f, __fsub_rn(pw, 1.0f));
  float hhf = __fmul_rn(0.5f, __fsub_rn(ph, 1.0f));
  x1 = __fsub_rn(pcx, hwf);
  x2 = __fadd_rn(pcx, hwf);
  y1 = __fsub_rn(pcy, hhf);
  y2 = __fadd_rn(pcy, hhf);
  x1 = fminf(fmaxf(x1, 0.0f), wlim);
  x2 = fminf(fmaxf(x2, 0.0f), wlim);
  y1 = fminf(fmaxf(y1, 0.0f), hlim);
  y2 = fminf(fmaxf(y2, 0.0f), hlim);
  valid = (__fadd_rn(__fsub_rn(x2, x1), 1.0f) >= 0.0f) &&
          (__fadd_rn(__fsub_rn(y2, y1), 1.0f) >= 0.0f);
}

// ---------- kernel 0: zero hist/cnt/cand ----------
__global__ void k_init(int* hist, int* cnt, unsigned long long* cand) {
  int i = blockIdx.x * blockDim.x + threadIdx.x;
  int n = blockDim.x * gridDim.x;
  for (int k = i; k < B_ * 4096; k += n) hist[k] = 0;
  for (int k = i; k < B_; k += n) cnt[k] = 0;
  for (int k = i; k < B_ * NCAND; k += n) cand[k] = 0ull;
}

// ---------- kernel A: masked scores + global histogram ----------
__global__ void k_scores(Ptrs P, const float* im_info, float* scores, int* hist) {
  int i = blockIdx.x * blockDim.x + threadIdx.x;
  int b = blockIdx.y;
  if (i >= N1) return;
  float wlim = __fsub_rn(im_info[b * 3 + 1], 1.0f);
  float hlim = __fsub_rn(im_info[b * 3 + 0], 1.0f);
  float x1, y1, x2, y2; bool valid;
  decode_one(P, b, i, wlim, hlim, x1, y1, x2, y2, valid);

  int lvl = (i >= c_OFF[4]) ? 4 : (i >= c_OFF[3]) ? 3 : (i >= c_OFF[2]) ? 2 : (i >= c_OFF[1]) ? 1 : 0;
  int rem = i - c_OFF[lvl];
  int a = rem % 3;
  int pos = rem / 3;
  int W = c_W[lvl];
  int h = pos / W, w = pos - h * W;
  size_t hw = (size_t)c_H[lvl] * W;
  float s = P.cls[lvl][((size_t)b * 6 + 3 + a) * hw + (size_t)h * W + w];
  float sv = valid ? s : NEGF;
  scores[(size_t)b * N1 + i] = sv;
  atomicAdd(&hist[b * 4096 + bucket_of(sv)], 1);
}

// ---------- kernel B1: cutoff bin per image (parallel suffix-sum) ----------
__global__ __launch_bounds__(1024) void k_cut(const int* hist, int* cutM) {
  int b = blockIdx.x, t = threadIdx.x;
  __shared__ int h[4096];
  __shared__ int ts[1024];
  __shared__ int s_cut, s_M;
  for (int i = t; i < 4096; i += 1024) h[i] = hist[b * 4096 + i];
  if (t == 0) { s_cut = -1; s_M = 0; }
  __syncthreads();
  int a0 = h[4 * t], a1 = h[4 * t + 1], a2 = h[4 * t + 2], a3 = h[4 * t + 3];
  ts[t] = a0 + a1 + a2 + a3;
  __syncthreads();
  // Hillis-Steele suffix sum over ts
  for (int off = 1; off < 1024; off <<= 1) {
    int v = ts[t] + ((t + off < 1024) ? ts[t + off] : 0);
    __syncthreads();
    ts[t] = v;
    __syncthreads();
  }
  int tail = (t + 1 < 1024) ? ts[t + 1] : 0;
  int s3 = a3 + tail, s2 = a2 + s3, s1 = a1 + s2, s0 = a0 + s1;
  int best = -1, Mv = 0;
  if      (s3 >= PRE) { best = 4 * t + 3; Mv = s3; }
  else if (s2 >= PRE) { best = 4 * t + 2; Mv = s2; }
  else if (s1 >= PRE) { best = 4 * t + 1; Mv = s1; }
  else if (s0 >= PRE) { best = 4 * t;     Mv = s0; }
  if (best >= 0) atomicMax(&s_cut, best);
  __syncthreads();
  if (s_cut == -1) { if (t == 0) { cutM[b * 2] = 0; cutM[b * 2 + 1] = ts[0]; } return; }
  if (best == s_cut) { cutM[b * 2] = best; cutM[b * 2 + 1] = Mv; }
}

// ---------- kernel B2: compact candidate keys (unordered) ----------
__global__ void k_compact(const float* scores, const int* cutM, int* cnt,
                          unsigned long long* cand) {
  int i = blockIdx.x * blockDim.x + threadIdx.x;
  int b = blockIdx.y;
  if (i >= N1) return;
  float s = scores[(size_t)b * N1 + i];
  if (bucket_of(s) >= cutM[b * 2]) {
    int p = atomicAdd(&cnt[b], 1);
    if (p < NCAND)
      cand[(size_t)b * NCAND + p] = ((unsigned long long)forder(s) << 32) |
                                    (unsigned long long)(0xFFFFFFFFu - (unsigned)i);
  }
}

// ---------- kernel B3: rank-and-scatter the top-PRE (exact sorted order) ----------
// Keys are unique (low bits embed the index), so rank = #{k' > k} is a
// permutation; the sorted top-PRE is a scatter. All-pairs count, LDS table.
__global__ __launch_bounds__(1024) void k_rank(const unsigned long long* __restrict__ cand,
                                               int* selIdx, float* selScore) {
  const int b = blockIdx.y;
  const int slot = blockIdx.x * 1024 + threadIdx.x;
  __shared__ unsigned long long tile[NCAND];   // 64 KB
  const unsigned long long* src = cand + (size_t)b * NCAND;
  for (int i = threadIdx.x; i < NCAND; i += 1024) tile[i] = src[i];
  __syncthreads();
  unsigned long long my = tile[slot];
  int rank = 0;
  #pragma unroll 8
  for (int j = 0; j < NCAND; ++j) rank += (tile[j] > my) ? 1 : 0;
  if (rank < PRE) {
    selIdx[(size_t)b * PRE + rank]   = (int)(0xFFFFFFFFu - (unsigned)(my & 0xFFFFFFFFull));
    selScore[(size_t)b * PRE + rank] = funorder((unsigned)(my >> 32));
  }
}

// ---------- kernel C: decode the selected 6000 boxes per image ----------
__global__ void k_decode(Ptrs P, const float* im_info, const int* selIdx, float* boxes) {
  int r = blockIdx.x * blockDim.x + threadIdx.x;
  int b = blockIdx.y;
  if (r >= PRE) return;
  float wlim = __fsub_rn(im_info[b * 3 + 1], 1.0f);
  float hlim = __fsub_rn(im_info[b * 3 + 0], 1.0f);
  int gi = selIdx[(size_t)b * PRE + r];
  float x1, y1, x2, y2; bool valid;
  decode_one(P, b, gi, wlim, hlim, x1, y1, x2, y2, valid);
  float* o = boxes + ((size_t)b * PRE + r) * 4;
  o[0] = x1; o[1] = y1; o[2] = x2; o[3] = y2;
}

// ---------- kernel D: IoU suppression bitmasks (zero-filled lower triangle) ----------
__global__ void k_mask(const float* boxes, unsigned long long* mask) {
  int cb = blockIdx.x, rb = blockIdx.y, b = blockIdx.z;
  int t = threadIdx.x;  // 64 threads
  __shared__ float cx1[64], cy1[64], cx2[64], cy2[64], car[64];
  int j0 = cb * 64;
  int jn = min(64, PRE - j0);
  if (cb >= rb && t < jn) {
    const float* bj = boxes + ((size_t)b * PRE + j0 + t) * 4;
    float a1 = bj[0], b1 = bj[1], a2 = bj[2], b2 = bj[3];
    cx1[t] = a1; cy1[t] = b1; cx2[t] = a2; cy2[t] = b2;
    car[t] = __fmul_rn(__fadd_rn(__fsub_rn(a2, a1), 1.0f),
                       __fadd_rn(__fsub_rn(b2, b1), 1.0f));
  }
  __syncthreads();
  int i = rb * 64 + t;
  if (i >= PRE) return;
  unsigned long long bits = 0;
  if (cb >= rb) {
    const float* bi = boxes + ((size_t)b * PRE + i) * 4;
    float x1 = bi[0], y1 = bi[1], x2 = bi[2], y2 = bi[3];
    float ai = __fmul_rn(__fadd_rn(__fsub_rn(x2, x1), 1.0f),
                         __fadd_rn(__fsub_rn(y2, y1), 1.0f));
    for (int jj = 0; jj < jn; ++jj) {
      int j = j0 + jj;
      if (j <= i) continue;
      float xx1 = fmaxf(x1, cx1[jj]);
      float yy1 = fmaxf(y1, cy1[jj]);
      float xx2 = fminf(x2, cx2[jj]);
      float yy2 = fminf(y2, cy2[jj]);
      float ww = fmaxf(__fadd_rn(__fsub_rn(xx2, xx1), 1.0f), 0.0f);
      float hh = fmaxf(__fadd_rn(__fsub_rn(yy2, yy1), 1.0f), 0.0f);
      float inter = __fmul_rn(ww, hh);
      float uni = __fsub_rn(__fadd_rn(ai, car[jj]), inter);
      float iou = __fdiv_rn(inter, uni);
      if (iou > 0.7f) bits |= (1ull << jj);
    }
  }
  mask[((size_t)b * PRE + i) * MWORDS + cb] = bits;
}

// ---------- kernel E: greedy scan — 16-wave TLP version ----------
__global__ __launch_bounds__(1024, 1) void k_scan(const unsigned long long* __restrict__ mask,
                                                  unsigned long long* __restrict__ rem) {
  const int b = blockIdx.x, tid = threadIdx.x;
  const unsigned long long* m = mask + (size_t)b * PRE * MWORDS;

  __shared__ unsigned long long s_diag[MWORDS * 64];  // 48 KB
  __shared__ unsigned long long s_rem[MWORDS];
  __shared__ unsigned long long s_alive;

  for (int i = tid; i < MWORDS * 64; i += 1024) {
    int rb = i >> 6, l = i & 63;
    int row = (rb << 6) + l;
    s_diag[i] = (row < PRE) ? m[(size_t)row * MWORDS + rb] : 0ull;
  }
  for (int i = tid; i < MWORDS; i += 1024) s_rem[i] = 0ull;
  __syncthreads();

  const int j  = tid % MWORDS;   // column word
  const int sp = tid / MWORDS;   // row split
  const bool active = sp < 8;

  unsigned long long cur[8] = {0,0,0,0,0,0,0,0}, nxt[8] = {0,0,0,0,0,0,0,0};

#define LOADTILE(BUF, RB)                                                      \
  if (active && (RB) < MWORDS && j >= (RB)) {                                  \
    _Pragma("unroll")                                                          \
    for (int t = 0; t < 8; ++t) {                                              \
      int row = ((RB) << 6) + sp * 8 + t;                                      \
      BUF[t] = (row < PRE) ? m[(size_t)row * MWORDS + j] : 0ull;               \
    }                                                                          \
  } else {                                                                     \
    _Pragma("unroll")                                                          \
    for (int t = 0; t < 8; ++t) BUF[t] = 0ull;                                 \
  }

  LOADTILE(cur, 0)
  for (int rb = 0; rb < MWORDS; ++rb) {
    LOADTILE(nxt, rb + 1)          // prefetch next tile (state-independent)

    if (tid < 64) {                // phase 1: serial aliveness on wave 0
      unsigned long long diag  = s_diag[(rb << 6) + tid];
      unsigned long long state = s_rem[rb];
      unsigned long long alive = 0;
      #pragma unroll
      for (int kk = 0; kk < 64; ++kk) {
        unsigned dlo = __builtin_amdgcn_readlane((unsigned)diag, kk);
        unsigned dhi = __builtin_amdgcn_readlane((unsigned)(diag >> 32), kk);
        unsigned long long d = ((unsigned long long)dhi << 32) | dlo;
        unsigned long long a = ((state >> kk) & 1ull) ^ 1ull;   // 1 if alive
        alive |= a << kk;
        state |= d & (0ull - a);
      }
      if (tid == 0) { s_rem[rb] = state; s_alive = alive; }
    }
    __syncthreads();

    if (active) {                  // phase 2: branchless masked OR
      unsigned long long alive = s_alive;
      unsigned long long acc = 0;
      #pragma unroll
      for (int t = 0; t < 8; ++t) {
        unsigned long long selm = 0ull - ((alive >> (sp * 8 + t)) & 1ull);
        acc |= cur[t] & selm;
      }
      if (acc) atomicOr(&s_rem[j], acc);
      #pragma unroll
      for (int t = 0; t < 8; ++t) cur[t] = nxt[t];
    }
    __syncthreads();
  }
#undef LOADTILE

  for (int i = tid; i < 128; i += 1024)
    rem[b * 128 + i] = (i < MWORDS) ? s_rem[i] : 0ull;
}

// ---------- kernel F: per-image post-NMS top-1000 via rank-and-scatter ----------
__global__ __launch_bounds__(1024) void k_post(const float* __restrict__ selScore,
                                               const unsigned long long* __restrict__ rem,
                                               unsigned long long* pk) {
  const int b = blockIdx.y;
  const int slot = blockIdx.x * 1024 + threadIdx.x;   // 6 blocks -> 6144 slots
  __shared__ unsigned long long tile[PRE];            // 48 KB
  const unsigned long long* rw = rem + b * 128;
  for (int i = threadIdx.x; i < PRE; i += 1024) {
    bool suppressed = (rw[i >> 6] >> (i & 63)) & 1ull;
    float s = suppressed ? NEGF : selScore[(size_t)b * PRE + i];
    unsigned tiev = 0xFFFFFFFFu - (unsigned)(b * 8192 + i);
    tile[i] = ((unsigned long long)forder(s) << 32) | (unsigned long long)tiev;
  }
  __syncthreads();
  unsigned long long my = (slot < PRE) ? tile[slot] : 0ull;
  int rank = 0;
  #pragma unroll 8
  for (int j = 0; j < PRE; ++j) rank += (tile[j] > my) ? 1 : 0;
  if (slot < PRE && rank < POST) pk[(size_t)b * POST + rank] = my;
}

// ---------- kernel G: global top-1000 of the 4000 via rank + gather ----------
__global__ __launch_bounds__(1024) void k_final(const unsigned long long* __restrict__ pk,
                                                const float* __restrict__ boxes, float* out) {
  const int slot = blockIdx.x * 1024 + threadIdx.x;   // 4 blocks -> 4096 slots
  __shared__ unsigned long long tile[4096];           // 32 KB
  for (int i = threadIdx.x; i < 4096; i += 1024)
    tile[i] = (i < B_ * POST) ? pk[i] : 0ull;
  __syncthreads();
  unsigned long long my = tile[slot];
  int rank = 0;
  #pragma unroll 8
  for (int j = 0; j < 4096; ++j) rank += (tile[j] > my) ? 1 : 0;
  if (slot < B_ * POST && rank < POST) {
    unsigned v = 0xFFFFFFFFu - (unsigned)(my & 0xFFFFFFFFull);
    int b = v >> 13, pos = v & 8191;
    float s = funorder((unsigned)(my >> 32));
    const float* bx = boxes + ((size_t)b * PRE + pos) * 4;
    out[rank * 5 + 0] = (float)b;
    out[rank * 5 + 1] = bx[0];
    out[rank * 5 + 2] = bx[1];
    out[rank * 5 + 3] = bx[2];
    out[rank * 5 + 4] = bx[3];
    out[5 * POST + rank] = s;
  }
}

// ---------- workspace layout (bytes, all 8-aligned) ----------
static constexpr size_t OFF_SC   = 0;                                  // B*N1 f32
static constexpr size_t OFF_SELS = OFF_SC   + (size_t)B_ * N1 * 4;     // B*PRE f32
static constexpr size_t OFF_SELI = OFF_SELS + (size_t)B_ * PRE * 4;    // B*PRE i32
static constexpr size_t OFF_BOX  = OFF_SELI + (size_t)B_ * PRE * 4;    // B*PRE*4 f32
static constexpr size_t OFF_MASK = OFF_BOX  + (size_t)B_ * PRE * 16;   // B*PRE*94 u64
static constexpr size_t OFF_REM  = OFF_MASK + (size_t)B_ * PRE * MWORDS * 8; // B*128 u64
static constexpr size_t OFF_PK   = OFF_REM  + (size_t)B_ * 128 * 8;    // B*POST u64
static constexpr size_t OFF_HIST = OFF_PK   + (size_t)B_ * POST * 8;   // B*4096 i32
static constexpr size_t OFF_CNT  = OFF_HIST + (size_t)B_ * 4096 * 4;   // B i32
static constexpr size_t OFF_CUTM = OFF_CNT  + (size_t)B_ * 8;          // B*2 i32
static constexpr size_t OFF_CAND = OFF_CUTM + (size_t)B_ * 8;          // B*NCAND u64

extern "C" void kernel_launch(void* const* d_in, const int* in_sizes, int n_in,
                              void* d_out, int out_size, void* d_ws, size_t ws_size,
                              hipStream_t stream) {
  Ptrs P;
  // setup_inputs() dict order is interleaved (cls_p2, bbox_p2, ...); detect defensively.
  bool interleaved = (n_in >= 2) && (in_sizes[1] == 2 * in_sizes[0]);
  for (int l = 0; l < 5; ++l) {
    if (interleaved) { P.cls[l] = (const float*)d_in[2 * l]; P.bbox[l] = (const float*)d_in[2 * l + 1]; }
    else             { P.cls[l] = (const float*)d_in[l];     P.bbox[l] = (const float*)d_in[5 + l]; }
  }
  const float* im_info = (const float*)d_in[10];

  char* ws = (char*)d_ws;
  float*              scores   = (float*)(ws + OFF_SC);
  float*              selScore = (float*)(ws + OFF_SELS);
  int*                selIdx   = (int*)(ws + OFF_SELI);
  float*              selBoxes = (float*)(ws + OFF_BOX);
  unsigned long long* maskBuf  = (unsigned long long*)(ws + OFF_MASK);
  unsigned long long* remBuf   = (unsigned long long*)(ws + OFF_REM);
  unsigned long long* postKeys = (unsigned long long*)(ws + OFF_PK);
  int*                histBuf  = (int*)(ws + OFF_HIST);
  int*                cntBuf   = (int*)(ws + OFF_CNT);
  int*                cutMBuf  = (int*)(ws + OFF_CUTM);
  unsigned long long* candBuf  = (unsigned long long*)(ws + OFF_CAND);
  float*              out      = (float*)d_out;

  k_init<<<64, 256, 0, stream>>>(histBuf, cntBuf, candBuf);
  k_scores<<<dim3((N1 + 255) / 256, B_), 256, 0, stream>>>(P, im_info, scores, histBuf);
  k_cut<<<B_, 1024, 0, stream>>>(histBuf, cutMBuf);
  k_compact<<<dim3((N1 + 255) / 256, B_), 256, 0, stream>>>(scores, cutMBuf, cntBuf, candBuf);
  k_rank<<<dim3(NCAND / 1024, B_), 1024, 0, stream>>>(candBuf, selIdx, selScore);
  k_decode<<<dim3((PRE + 255) / 256, B_), 256, 0, stream>>>(P, im_info, selIdx, selBoxes);
  k_mask<<<dim3(MWORDS, MWORDS, B_), 64, 0, stream>>>(selBoxes, maskBuf);
  k_scan<<<B_, 1024, 0, stream>>>(maskBuf, remBuf);
  k_post<<<dim3(6, B_), 1024, 0, stream>>>(selScore, remBuf, postKeys);
  k_final<<<4, 1024, 0, stream>>>(postKeys, selBoxes, out);
}

// Round 6
// 598.355 us; speedup vs baseline: 1.4583x; 1.4583x over previous
//
#include <hip/hip_runtime.h>
#include <stdint.h>
#include <math.h>

static constexpr int B_   = 4;
static constexpr int N1   = 255780;   // total anchors per image across 5 levels
static constexpr int PRE  = 6000;
static constexpr int PREP = 6016;     // padded rows (multiple of 64) for tile DMA
static constexpr int POST = 1000;
static constexpr int MWORDS = 94;     // ceil(6000/64)
static constexpr int NCAND = 8192;    // candidate capacity per image
static constexpr int NPOSTS = 6144;   // padded post-slot count
static constexpr float NEGF = -1000000000.0f;

#define GLOBAL_AS __attribute__((address_space(1)))
#define LDS_AS    __attribute__((address_space(3)))

__device__ __constant__ int c_OFF[6] = {0,192000,240000,252000,255000,255780};
__device__ __constant__ int c_H[5]   = {200,100,50,25,13};
__device__ __constant__ int c_W[5]   = {320,160,80,40,20};
__device__ __constant__ int c_S[5]   = {4,8,16,32,64};

struct Ptrs { const float* cls[5]; const float* bbox[5]; };

// ---------- helpers ----------
__device__ __forceinline__ unsigned forder(float f) {
  unsigned u = __float_as_uint(f);
  return (u & 0x80000000u) ? ~u : (u | 0x80000000u);
}
__device__ __forceinline__ float funorder(unsigned u) {
  u = (u & 0x80000000u) ? (u & 0x7FFFFFFFu) : ~u;
  return __uint_as_float(u);
}
__device__ __forceinline__ int bucket_of(float s) {
  int bk = (int)(s * 4096.0f);
  return max(0, min(4095, bk));
}

// base anchor (legacy +1 convention), double math == numpy float64, rint == np.round
__device__ __forceinline__ void anchor_for(int lvl, int a, float& ax1, float& ay1, float& ax2, float& ay2) {
  int st = c_S[lvl];
  double size = (double)st * (double)st;
  double c = 0.5 * (double)(st - 1);
  double r = (a == 0) ? 0.5 : (a == 1) ? 1.0 : 2.0;
  double ws = rint(sqrt(size / r));
  double hs = rint(ws * r);
  double w2 = ws * 8.0, h2 = hs * 8.0;
  ax1 = (float)(c - 0.5 * (w2 - 1.0));
  ay1 = (float)(c - 0.5 * (h2 - 1.0));
  ax2 = (float)(c + 0.5 * (w2 - 1.0));
  ay2 = (float)(c + 0.5 * (h2 - 1.0));
}

// decode one anchor exactly as the reference (per-op f32 rounding, no FMA)
__device__ __forceinline__ void decode_one(const Ptrs& P, int b, int gi, float wlim, float hlim,
                                           float& x1, float& y1, float& x2, float& y2, bool& valid) {
  int lvl = (gi >= c_OFF[4]) ? 4 : (gi >= c_OFF[3]) ? 3 : (gi >= c_OFF[2]) ? 2 : (gi >= c_OFF[1]) ? 1 : 0;
  int rem = gi - c_OFF[lvl];
  int a = rem % 3;
  int pos = rem / 3;
  int W = c_W[lvl];
  int h = pos / W, w = pos - h * W;
  size_t hw = (size_t)c_H[lvl] * W;
  const float* bb = P.bbox[lvl] + ((size_t)b * 12 + 4 * a) * hw + (size_t)h * W + w;
  float d0 = bb[0], d1 = bb[hw], d2 = bb[2 * hw], d3 = bb[3 * hw];

  float ax1, ay1, ax2, ay2;
  anchor_for(lvl, a, ax1, ay1, ax2, ay2);
  int st = c_S[lvl];
  float sx = (float)(w * st), sy = (float)(h * st);
  ax1 += sx; ax2 += sx; ay1 += sy; ay2 += sy;   // exact integers

  float aw  = __fadd_rn(__fsub_rn(ax2, ax1), 1.0f);
  float ah  = __fadd_rn(__fsub_rn(ay2, ay1), 1.0f);
  float acx = __fadd_rn(ax1, __fmul_rn(0.5f, __fsub_rn(aw, 1.0f)));
  float acy = __fadd_rn(ay1, __fmul_rn(0.5f, __fsub_rn(ah, 1.0f)));
  float ew  = (float)exp((double)d2);
  float eh  = (float)exp((double)d3);
  float pcx = __fadd_rn(__fmul_rn(d0, aw), acx);
  float pcy = __fadd_rn(__fmul_rn(d1, ah), acy);
  float pw  = __fmul_rn(ew, aw);
  float ph  = __fmul_rn(eh, ah);
  float hwf = __fmul_rn(0.5f, __fsub_rn(pw, 1.0f));
  float hhf = __fmul_rn(0.5f, __fsub_rn(ph, 1.0f));
  x1 = __fsub_rn(pcx, hwf);
  x2 = __fadd_rn(pcx, hwf);
  y1 = __fsub_rn(pcy, hhf);
  y2 = __fadd_rn(pcy, hhf);
  x1 = fminf(fmaxf(x1, 0.0f), wlim);
  x2 = fminf(fmaxf(x2, 0.0f), wlim);
  y1 = fminf(fmaxf(y1, 0.0f), hlim);
  y2 = fminf(fmaxf(y2, 0.0f), hlim);
  valid = (__fadd_rn(__fsub_rn(x2, x1), 1.0f) >= 0.0f) &&
          (__fadd_rn(__fsub_rn(y2, y1), 1.0f) >= 0.0f);
}

// ---------- kernel 0: zero hist/cnt/cand/ranks + mask padding rows ----------
__global__ void k_init(int* hist, int* cnt, unsigned long long* cand,
                       int* rankA, int* rankB, int* rankC, unsigned long long* mask) {
  int i = blockIdx.x * blockDim.x + threadIdx.x;
  int n = blockDim.x * gridDim.x;
  for (int k = i; k < B_ * 4096; k += n) hist[k] = 0;
  for (int k = i; k < B_; k += n) cnt[k] = 0;
  for (int k = i; k < B_ * NCAND; k += n) cand[k] = 0ull;
  for (int k = i; k < B_ * NCAND; k += n) rankA[k] = 0;
  for (int k = i; k < B_ * NPOSTS; k += n) rankB[k] = 0;
  for (int k = i; k < 4096; k += n) rankC[k] = 0;
  // zero padding rows PRE..PREP-1 of each image
  int padw = (PREP - PRE) * MWORDS;          // 16*94
  for (int k = i; k < B_ * padw; k += n) {
    int bb = k / padw, r = k % padw;
    mask[((size_t)bb * PREP + PRE) * MWORDS + r] = 0ull;
  }
}

// ---------- kernel A: masked scores + global histogram ----------
__global__ void k_scores(Ptrs P, const float* im_info, float* scores, int* hist) {
  int i = blockIdx.x * blockDim.x + threadIdx.x;
  int b = blockIdx.y;
  if (i >= N1) return;
  float wlim = __fsub_rn(im_info[b * 3 + 1], 1.0f);
  float hlim = __fsub_rn(im_info[b * 3 + 0], 1.0f);
  float x1, y1, x2, y2; bool valid;
  decode_one(P, b, i, wlim, hlim, x1, y1, x2, y2, valid);

  int lvl = (i >= c_OFF[4]) ? 4 : (i >= c_OFF[3]) ? 3 : (i >= c_OFF[2]) ? 2 : (i >= c_OFF[1]) ? 1 : 0;
  int rem = i - c_OFF[lvl];
  int a = rem % 3;
  int pos = rem / 3;
  int W = c_W[lvl];
  int h = pos / W, w = pos - h * W;
  size_t hw = (size_t)c_H[lvl] * W;
  float s = P.cls[lvl][((size_t)b * 6 + 3 + a) * hw + (size_t)h * W + w];
  float sv = valid ? s : NEGF;
  scores[(size_t)b * N1 + i] = sv;
  atomicAdd(&hist[b * 4096 + bucket_of(sv)], 1);
}

// ---------- kernel B1: cutoff bin per image (parallel suffix-sum) ----------
__global__ __launch_bounds__(1024) void k_cut(const int* hist, int* cutM) {
  int b = blockIdx.x, t = threadIdx.x;
  __shared__ int h[4096];
  __shared__ int ts[1024];
  __shared__ int s_cut, s_M;
  for (int i = t; i < 4096; i += 1024) h[i] = hist[b * 4096 + i];
  if (t == 0) { s_cut = -1; s_M = 0; }
  __syncthreads();
  int a0 = h[4 * t], a1 = h[4 * t + 1], a2 = h[4 * t + 2], a3 = h[4 * t + 3];
  ts[t] = a0 + a1 + a2 + a3;
  __syncthreads();
  for (int off = 1; off < 1024; off <<= 1) {
    int v = ts[t] + ((t + off < 1024) ? ts[t + off] : 0);
    __syncthreads();
    ts[t] = v;
    __syncthreads();
  }
  int tail = (t + 1 < 1024) ? ts[t + 1] : 0;
  int s3 = a3 + tail, s2 = a2 + s3, s1 = a1 + s2, s0 = a0 + s1;
  int best = -1, Mv = 0;
  if      (s3 >= PRE) { best = 4 * t + 3; Mv = s3; }
  else if (s2 >= PRE) { best = 4 * t + 2; Mv = s2; }
  else if (s1 >= PRE) { best = 4 * t + 1; Mv = s1; }
  else if (s0 >= PRE) { best = 4 * t;     Mv = s0; }
  if (best >= 0) atomicMax(&s_cut, best);
  __syncthreads();
  if (s_cut == -1) { if (t == 0) { cutM[b * 2] = 0; cutM[b * 2 + 1] = ts[0]; } return; }
  if (best == s_cut) { cutM[b * 2] = best; cutM[b * 2 + 1] = Mv; }
}

// ---------- kernel B2: compact candidate keys (unordered) ----------
__global__ void k_compact(const float* scores, const int* cutM, int* cnt,
                          unsigned long long* cand) {
  int i = blockIdx.x * blockDim.x + threadIdx.x;
  int b = blockIdx.y;
  if (i >= N1) return;
  float s = scores[(size_t)b * N1 + i];
  if (bucket_of(s) >= cutM[b * 2]) {
    int p = atomicAdd(&cnt[b], 1);
    if (p < NCAND)
      cand[(size_t)b * NCAND + p] = ((unsigned long long)forder(s) << 32) |
                                    (unsigned long long)(0xFFFFFFFFu - (unsigned)i);
  }
}

// ---------- kernel B3a: partial ranks (chunked all-pairs, many CUs) ----------
__global__ __launch_bounds__(1024) void k_rankp(const unsigned long long* __restrict__ cand,
                                                int* __restrict__ rankA) {
  const int b = blockIdx.y;
  const int sc = blockIdx.x >> 3, jc = blockIdx.x & 7;
  __shared__ __align__(16) unsigned long long tile[1024];
  const unsigned long long* src = cand + (size_t)b * NCAND;
  tile[threadIdx.x] = src[jc * 1024 + threadIdx.x];
  __syncthreads();
  unsigned long long my = src[sc * 1024 + threadIdx.x];
  int r = 0;
  const ulonglong2* t2 = (const ulonglong2*)tile;
  #pragma unroll 8
  for (int t = 0; t < 512; ++t) { ulonglong2 v = t2[t]; r += (v.x > my) + (v.y > my); }
  atomicAdd(&rankA[b * NCAND + sc * 1024 + threadIdx.x], r);
}

// ---------- kernel B3b: scatter by rank ----------
__global__ void k_ranks(const unsigned long long* cand, const int* rankA,
                        int* selIdx, float* selScore) {
  int b = blockIdx.y, slot = blockIdx.x * 256 + threadIdx.x;
  unsigned long long my = cand[(size_t)b * NCAND + slot];
  int r = rankA[b * NCAND + slot];
  if (r < PRE) {
    selIdx[(size_t)b * PRE + r]   = (int)(0xFFFFFFFFu - (unsigned)(my & 0xFFFFFFFFull));
    selScore[(size_t)b * PRE + r] = funorder((unsigned)(my >> 32));
  }
}

// ---------- kernel C: decode the selected 6000 boxes per image ----------
__global__ void k_decode(Ptrs P, const float* im_info, const int* selIdx, float* boxes) {
  int r = blockIdx.x * blockDim.x + threadIdx.x;
  int b = blockIdx.y;
  if (r >= PRE) return;
  float wlim = __fsub_rn(im_info[b * 3 + 1], 1.0f);
  float hlim = __fsub_rn(im_info[b * 3 + 0], 1.0f);
  int gi = selIdx[(size_t)b * PRE + r];
  float x1, y1, x2, y2; bool valid;
  decode_one(P, b, gi, wlim, hlim, x1, y1, x2, y2, valid);
  float* o = boxes + ((size_t)b * PRE + r) * 4;
  o[0] = x1; o[1] = y1; o[2] = x2; o[3] = y2;
}

// ---------- kernel D: IoU suppression bitmasks (zero-filled lower triangle) ----------
__global__ void k_mask(const float* boxes, unsigned long long* mask) {
  int cb = blockIdx.x, rb = blockIdx.y, b = blockIdx.z;
  int t = threadIdx.x;  // 64 threads
  __shared__ float cx1[64], cy1[64], cx2[64], cy2[64], car[64];
  int j0 = cb * 64;
  int jn = min(64, PRE - j0);
  if (cb >= rb && t < jn) {
    const float* bj = boxes + ((size_t)b * PRE + j0 + t) * 4;
    float a1 = bj[0], b1 = bj[1], a2 = bj[2], b2 = bj[3];
    cx1[t] = a1; cy1[t] = b1; cx2[t] = a2; cy2[t] = b2;
    car[t] = __fmul_rn(__fadd_rn(__fsub_rn(a2, a1), 1.0f),
                       __fadd_rn(__fsub_rn(b2, b1), 1.0f));
  }
  __syncthreads();
  int i = rb * 64 + t;
  if (i >= PRE) return;
  unsigned long long bits = 0;
  if (cb >= rb) {
    const float* bi = boxes + ((size_t)b * PRE + i) * 4;
    float x1 = bi[0], y1 = bi[1], x2 = bi[2], y2 = bi[3];
    float ai = __fmul_rn(__fadd_rn(__fsub_rn(x2, x1), 1.0f),
                         __fadd_rn(__fsub_rn(y2, y1), 1.0f));
    for (int jj = 0; jj < jn; ++jj) {
      int j = j0 + jj;
      if (j <= i) continue;
      float xx1 = fmaxf(x1, cx1[jj]);
      float yy1 = fmaxf(y1, cy1[jj]);
      float xx2 = fminf(x2, cx2[jj]);
      float yy2 = fminf(y2, cy2[jj]);
      float ww = fmaxf(__fadd_rn(__fsub_rn(xx2, xx1), 1.0f), 0.0f);
      float hh = fmaxf(__fadd_rn(__fsub_rn(yy2, yy1), 1.0f), 0.0f);
      float inter = __fmul_rn(ww, hh);
      float uni = __fsub_rn(__fadd_rn(ai, car[jj]), inter);
      float iou = __fdiv_rn(inter, uni);
      if (iou > 0.7f) bits |= (1ull << jj);
    }
  }
  mask[((size_t)b * PREP + i) * MWORDS + cb] = bits;
}

// ---------- kernel E: greedy scan — LDS-DMA double-buffered tiles ----------
// One 1024-thread block per image. Tile rb = 64 mask rows (47KB contiguous)
// DMA'd to LDS via global_load_lds (no VGPR footprint -> compiler can't sink
// it). Prefetch for rb+1 is issued at iter top; the compiler's vmcnt drain at
// the phase-1 barrier is the latency cover. Phase 1 = serial aliveness chain
// (register/LDS only); phase 2 = branchless OR of alive rows from LDS.
__global__ __launch_bounds__(1024, 1) void k_scan(const unsigned long long* __restrict__ mask,
                                                  unsigned long long* __restrict__ rem) {
  const int b = blockIdx.x, tid = threadIdx.x;
  const int w = tid >> 6, l = tid & 63;
  const unsigned long long* m = mask + (size_t)b * PREP * MWORDS;

  __shared__ unsigned long long s_tile[2][64 * MWORDS];  // 2 x 47KB
  __shared__ unsigned long long s_rem[MWORDS];
  __shared__ unsigned long long s_alive;

  for (int i = tid; i < MWORDS; i += 1024) s_rem[i] = 0ull;

  // DMA tile 0 into buffer 0 (slab of 64 rows = 48128 B = 47 chunks of 1KB)
  {
    const char* src = (const char*)m;
    char* dst = (char*)&s_tile[0][0];
    for (int c = w; c < 47; c += 16) {
      __builtin_amdgcn_global_load_lds(
          (const GLOBAL_AS unsigned int*)(src + c * 1024 + l * 16),
          (LDS_AS unsigned int*)(dst + c * 1024), 16, 0, 0);
    }
  }
  __syncthreads();

  const int j  = tid % MWORDS;   // column word
  const int sp = tid / MWORDS;   // row split
  const bool active = sp < 8;

  int cur = 0;
  for (int rb = 0; rb < MWORDS; ++rb) {
    // prefetch next tile into the other buffer (state-independent)
    if (rb + 1 < MWORDS) {
      const char* src = (const char*)(m + (size_t)(rb + 1) * 64 * MWORDS);
      char* dst = (char*)&s_tile[cur ^ 1][0];
      for (int c = w; c < 47; c += 16) {
        __builtin_amdgcn_global_load_lds(
            (const GLOBAL_AS unsigned int*)(src + c * 1024 + l * 16),
            (LDS_AS unsigned int*)(dst + c * 1024), 16, 0, 0);
      }
    }

    if (tid < 64) {                // phase 1: serial aliveness on wave 0
      unsigned long long diag  = s_tile[cur][tid * MWORDS + rb];
      unsigned long long state = s_rem[rb];
      unsigned long long alive = 0;
      #pragma unroll
      for (int kk = 0; kk < 64; ++kk) {
        unsigned dlo = __builtin_amdgcn_readlane((unsigned)diag, kk);
        unsigned dhi = __builtin_amdgcn_readlane((unsigned)(diag >> 32), kk);
        unsigned long long d = ((unsigned long long)dhi << 32) | dlo;
        unsigned long long a = ((state >> kk) & 1ull) ^ 1ull;   // 1 if alive
        alive |= a << kk;
        state |= d & (0ull - a);
      }
      if (tid == 0) { s_rem[rb] = state; s_alive = alive; }
    }
    __syncthreads();               // also drains the tile DMA (vmcnt 0)

    if (active && j >= rb) {       // phase 2: branchless masked OR from LDS
      unsigned long long alive = s_alive;
      unsigned long long acc = 0;
      #pragma unroll
      for (int t = 0; t < 8; ++t) {
        unsigned long long selm = 0ull - ((alive >> (sp * 8 + t)) & 1ull);
        acc |= s_tile[cur][(sp * 8 + t) * MWORDS + j] & selm;
      }
      if (acc) atomicOr(&s_rem[j], acc);
    }
    __syncthreads();
    cur ^= 1;
  }

  for (int i = tid; i < 128; i += 1024)
    rem[b * 128 + i] = (i < MWORDS) ? s_rem[i] : 0ull;
}

// ---------- post-NMS keys ----------
__device__ __forceinline__ unsigned long long post_key(const float* selScore,
                                                       const unsigned long long* rw,
                                                       int b, int i) {
  if (i >= PRE) return 0ull;
  bool sup = (rw[i >> 6] >> (i & 63)) & 1ull;
  float s = sup ? NEGF : selScore[(size_t)b * PRE + i];
  unsigned tiev = 0xFFFFFFFFu - (unsigned)(b * 8192 + i);
  return ((unsigned long long)forder(s) << 32) | (unsigned long long)tiev;
}

// ---------- kernel F: per-image post-NMS top-1000, chunked partial ranks ----------
__global__ __launch_bounds__(1024) void k_postp(const float* __restrict__ selScore,
                                                const unsigned long long* __restrict__ rem,
                                                int* __restrict__ rankB) {
  const int b = blockIdx.y;
  const int sc = blockIdx.x / 6, jc = blockIdx.x % 6;
  __shared__ __align__(16) unsigned long long tile[1024];
  const unsigned long long* rw = rem + b * 128;
  tile[threadIdx.x] = post_key(selScore, rw, b, jc * 1024 + threadIdx.x);
  __syncthreads();
  int slot = sc * 1024 + threadIdx.x;
  unsigned long long my = post_key(selScore, rw, b, slot);
  int r = 0;
  const ulonglong2* t2 = (const ulonglong2*)tile;
  #pragma unroll 8
  for (int t = 0; t < 512; ++t) { ulonglong2 v = t2[t]; r += (v.x > my) + (v.y > my); }
  if (slot < PRE) atomicAdd(&rankB[b * NPOSTS + slot], r);
}

__global__ void k_posts(const float* selScore, const unsigned long long* rem,
                        const int* rankB, unsigned long long* pk) {
  int b = blockIdx.y, slot = blockIdx.x * 256 + threadIdx.x;
  if (slot >= PRE) return;
  int r = rankB[b * NPOSTS + slot];
  if (r < POST) pk[(size_t)b * POST + r] = post_key(selScore, rem + b * 128, b, slot);
}

// ---------- kernel G: global top-1000 of the 4000, chunked partial ranks ----------
__global__ __launch_bounds__(1024) void k_finp(const unsigned long long* __restrict__ pk,
                                               int* __restrict__ rankC) {
  const int sc = blockIdx.x >> 2, jc = blockIdx.x & 3;
  __shared__ __align__(16) unsigned long long tile[1024];
  int ji = jc * 1024 + threadIdx.x;
  tile[threadIdx.x] = (ji < B_ * POST) ? pk[ji] : 0ull;
  __syncthreads();
  int slot = sc * 1024 + threadIdx.x;
  unsigned long long my = (slot < B_ * POST) ? pk[slot] : 0ull;
  int r = 0;
  const ulonglong2* t2 = (const ulonglong2*)tile;
  #pragma unroll 8
  for (int t = 0; t < 512; ++t) { ulonglong2 v = t2[t]; r += (v.x > my) + (v.y > my); }
  if (slot < B_ * POST) atomicAdd(&rankC[slot], r);
}

__global__ void k_fins(const unsigned long long* pk, const int* rankC,
                       const float* boxes, float* out) {
  int slot = blockIdx.x * 256 + threadIdx.x;
  if (slot >= B_ * POST) return;
  int r = rankC[slot];
  if (r < POST) {
    unsigned long long my = pk[slot];
    unsigned v = 0xFFFFFFFFu - (unsigned)(my & 0xFFFFFFFFull);
    int b = v >> 13, pos = v & 8191;
    float s = funorder((unsigned)(my >> 32));
    const float* bx = boxes + ((size_t)b * PRE + pos) * 4;
    out[r * 5 + 0] = (float)b;
    out[r * 5 + 1] = bx[0];
    out[r * 5 + 2] = bx[1];
    out[r * 5 + 3] = bx[2];
    out[r * 5 + 4] = bx[3];
    out[5 * POST + r] = s;
  }
}

// ---------- workspace layout (bytes, all 16-aligned) ----------
static constexpr size_t OFF_SC   = 0;                                    // B*N1 f32
static constexpr size_t OFF_SELS = OFF_SC   + (size_t)B_ * N1 * 4;       // B*PRE f32
static constexpr size_t OFF_SELI = OFF_SELS + (size_t)B_ * PRE * 4;      // B*PRE i32
static constexpr size_t OFF_BOX  = OFF_SELI + (size_t)B_ * PRE * 4;      // B*PRE*4 f32
static constexpr size_t OFF_MASK = OFF_BOX  + (size_t)B_ * PRE * 16;     // B*PREP*94 u64
static constexpr size_t OFF_REM  = OFF_MASK + (size_t)B_ * PREP * MWORDS * 8; // B*128 u64
static constexpr size_t OFF_PK   = OFF_REM  + (size_t)B_ * 128 * 8;      // B*POST u64
static constexpr size_t OFF_HIST = OFF_PK   + (size_t)B_ * POST * 8;     // B*4096 i32
static constexpr size_t OFF_CNT  = OFF_HIST + (size_t)B_ * 4096 * 4;     // B i32 (pad 16)
static constexpr size_t OFF_CUTM = OFF_CNT  + 16;                        // B*2 i32 (pad 32)
static constexpr size_t OFF_CAND = OFF_CUTM + 32;                        // B*NCAND u64
static constexpr size_t OFF_RKA  = OFF_CAND + (size_t)B_ * NCAND * 8;    // B*NCAND i32
static constexpr size_t OFF_RKB  = OFF_RKA  + (size_t)B_ * NCAND * 4;    // B*NPOSTS i32
static constexpr size_t OFF_RKC  = OFF_RKB  + (size_t)B_ * NPOSTS * 4;   // 4096 i32

extern "C" void kernel_launch(void* const* d_in, const int* in_sizes, int n_in,
                              void* d_out, int out_size, void* d_ws, size_t ws_size,
                              hipStream_t stream) {
  Ptrs P;
  bool interleaved = (n_in >= 2) && (in_sizes[1] == 2 * in_sizes[0]);
  for (int l = 0; l < 5; ++l) {
    if (interleaved) { P.cls[l] = (const float*)d_in[2 * l]; P.bbox[l] = (const float*)d_in[2 * l + 1]; }
    else             { P.cls[l] = (const float*)d_in[l];     P.bbox[l] = (const float*)d_in[5 + l]; }
  }
  const float* im_info = (const float*)d_in[10];

  char* ws = (char*)d_ws;
  float*              scores   = (float*)(ws + OFF_SC);
  float*              selScore = (float*)(ws + OFF_SELS);
  int*                selIdx   = (int*)(ws + OFF_SELI);
  float*              selBoxes = (float*)(ws + OFF_BOX);
  unsigned long long* maskBuf  = (unsigned long long*)(ws + OFF_MASK);
  unsigned long long* remBuf   = (unsigned long long*)(ws + OFF_REM);
  unsigned long long* postKeys = (unsigned long long*)(ws + OFF_PK);
  int*                histBuf  = (int*)(ws + OFF_HIST);
  int*                cntBuf   = (int*)(ws + OFF_CNT);
  int*                cutMBuf  = (int*)(ws + OFF_CUTM);
  unsigned long long* candBuf  = (unsigned long long*)(ws + OFF_CAND);
  int*                rankA    = (int*)(ws + OFF_RKA);
  int*                rankB    = (int*)(ws + OFF_RKB);
  int*                rankC    = (int*)(ws + OFF_RKC);
  float*              out      = (float*)d_out;

  k_init<<<128, 256, 0, stream>>>(histBuf, cntBuf, candBuf, rankA, rankB, rankC, maskBuf);
  k_scores<<<dim3((N1 + 255) / 256, B_), 256, 0, stream>>>(P, im_info, scores, histBuf);
  k_cut<<<B_, 1024, 0, stream>>>(histBuf, cutMBuf);
  k_compact<<<dim3((N1 + 255) / 256, B_), 256, 0, stream>>>(scores, cutMBuf, cntBuf, candBuf);
  k_rankp<<<dim3(64, B_), 1024, 0, stream>>>(candBuf, rankA);
  k_ranks<<<dim3(NCAND / 256, B_), 256, 0, stream>>>(candBuf, rankA, selIdx, selScore);
  k_decode<<<dim3((PRE + 255) / 256, B_), 256, 0, stream>>>(P, im_info, selIdx, selBoxes);
  k_mask<<<dim3(MWORDS, MWORDS, B_), 64, 0, stream>>>(selBoxes, maskBuf);
  k_scan<<<B_, 1024, 0, stream>>>(maskBuf, remBuf);
  k_postp<<<dim3(36, B_), 1024, 0, stream>>>(selScore, remBuf, rankB);
  k_posts<<<dim3(NPOSTS / 256, B_), 256, 0, stream>>>(selScore, remBuf, rankB, postKeys);
  k_finp<<<16, 1024, 0, stream>>>(postKeys, rankC);
  k_fins<<<16, 256, 0, stream>>>(postKeys, rankC, selBoxes, out);
}